// Round 14
// baseline (143.794 us; speedup 1.0000x reference)
//
#include <hip/hip_runtime.h>

typedef __attribute__((ext_vector_type(4)))  float f32x4;
typedef __attribute__((ext_vector_type(16))) float f32x16;
typedef __attribute__((ext_vector_type(8)))  short short8;

#define DD 256          // feature dim
#define CC 512          // num classes
#define LDP2 264        // padded LDS row stride (bf16 elems): 528B

__device__ __forceinline__ unsigned short f2bf(float f) {
    union { float f; unsigned u; } x; x.f = f;
    unsigned r = x.u + 0x7FFFu + ((x.u >> 16) & 1u);   // RNE
    return (unsigned short)(r >> 16);
}

__device__ __forceinline__ f32x4 ntload4(const f32x4* p) {
    return __builtin_nontemporal_load(p);   // ext_vector type: accepted by the builtin
}

// ---------------- K1: per-class segment sum of normalized support rows ----------------
__global__ __launch_bounds__(256) void class_sum_kernel(
    const f32x4* __restrict__ S, const int* __restrict__ labels,
    float* __restrict__ sums2, float* __restrict__ counts2, int N_s)
{
    const int c = blockIdx.x >> 1, half = blockIdx.x & 1;
    const int w = threadIdx.x >> 6, l = threadIdx.x & 63;
    const int seg  = N_s >> 3;
    const int base = half * (N_s >> 1) + w * seg;
    const int4* lab4 = (const int4*)(labels + base);
    const int iters = seg >> 8;

    float ax = 0.f, ay = 0.f, az = 0.f, aw = 0.f;
    int cnt = 0;

    int4 pf0 = lab4[l];
    int4 pf1 = (iters > 1) ? lab4[64 + l] : make_int4(-1, -1, -1, -1);

    for (int it = 0; it < iters; ++it) {
        int4 lv = pf0;
        pf0 = pf1;
        pf1 = (it + 2 < iters) ? lab4[(it + 2) * 64 + l] : make_int4(-1, -1, -1, -1);
        #pragma unroll
        for (int s = 0; s < 4; ++s) {
            int lab = (s == 0) ? lv.x : (s == 1) ? lv.y : (s == 2) ? lv.z : lv.w;
            unsigned long long m = __ballot(lab == c);
            cnt += __popcll(m);
            while (m) {
                int p0 = __ffsll((long long)m) - 1; m &= m - 1;
                int p1 = -1, p2 = -1, p3 = -1;
                if (m) { p1 = __ffsll((long long)m) - 1; m &= m - 1;
                    if (m) { p2 = __ffsll((long long)m) - 1; m &= m - 1;
                        if (m) { p3 = __ffsll((long long)m) - 1; m &= m - 1; } } }
                f32x4 v0 = ntload4(&S[(size_t)(base + (it * 64 + p0) * 4 + s) * 64 + l]);
                f32x4 v1 = {0,0,0,0}, v2 = {0,0,0,0}, v3 = {0,0,0,0};
                if (p1 >= 0) v1 = ntload4(&S[(size_t)(base + (it * 64 + p1) * 4 + s) * 64 + l]);
                if (p2 >= 0) v2 = ntload4(&S[(size_t)(base + (it * 64 + p2) * 4 + s) * 64 + l]);
                if (p3 >= 0) v3 = ntload4(&S[(size_t)(base + (it * 64 + p3) * 4 + s) * 64 + l]);
                float s0 = v0[0]*v0[0] + v0[1]*v0[1] + v0[2]*v0[2] + v0[3]*v0[3];
                float s1 = v1[0]*v1[0] + v1[1]*v1[1] + v1[2]*v1[2] + v1[3]*v1[3];
                float s2 = v2[0]*v2[0] + v2[1]*v2[1] + v2[2]*v2[2] + v2[3]*v2[3];
                float s3 = v3[0]*v3[0] + v3[1]*v3[1] + v3[2]*v3[2] + v3[3]*v3[3];
                #pragma unroll
                for (int off = 32; off; off >>= 1) {
                    s0 += __shfl_xor(s0, off);
                    s1 += __shfl_xor(s1, off);
                    s2 += __shfl_xor(s2, off);
                    s3 += __shfl_xor(s3, off);
                }
                float i0 = 1.0f / fmaxf(sqrtf(s0), 1e-8f);
                ax += v0[0]*i0; ay += v0[1]*i0; az += v0[2]*i0; aw += v0[3]*i0;
                if (p1 >= 0) { float i1 = 1.0f / fmaxf(sqrtf(s1), 1e-8f);
                    ax += v1[0]*i1; ay += v1[1]*i1; az += v1[2]*i1; aw += v1[3]*i1; }
                if (p2 >= 0) { float i2 = 1.0f / fmaxf(sqrtf(s2), 1e-8f);
                    ax += v2[0]*i2; ay += v2[1]*i2; az += v2[2]*i2; aw += v2[3]*i2; }
                if (p3 >= 0) { float i3 = 1.0f / fmaxf(sqrtf(s3), 1e-8f);
                    ax += v3[0]*i3; ay += v3[1]*i3; az += v3[2]*i3; aw += v3[3]*i3; }
            }
        }
    }

    __shared__ float lred[4][DD];
    __shared__ float lcnt[4];
    lred[w][4*l+0] = ax; lred[w][4*l+1] = ay; lred[w][4*l+2] = az; lred[w][4*l+3] = aw;
    if (l == 0) lcnt[w] = (float)cnt;
    __syncthreads();
    int t = threadIdx.x;
    sums2[(size_t)(half * CC + c) * DD + t] = lred[0][t] + lred[1][t] + lred[2][t] + lred[3][t];
    if (t == 0) counts2[half * CC + c] = lcnt[0] + lcnt[1] + lcnt[2] + lcnt[3];
}

// ---------------- K2: centroid partials (8 blocks, no atomics) ----------------
__global__ __launch_bounds__(256) void centroid_kernel(
    const float* __restrict__ sums2, float* __restrict__ gpart)
{
    const int d = threadIdx.x, b = blockIdx.x;
    float s = 0.f;
    for (int j = 0; j < 64; ++j) {
        int c = b * 64 + j;
        s += sums2[(size_t)c * DD + d] + sums2[(size_t)(CC + c) * DD + d];
    }
    gpart[b * DD + d] = s;
}

// ---------------- K3: prototypes -> bf16 Pt in MFMA B-frag layout, SCALE FOLDED IN ----
// Pt element for (class c, dim d):
//   CT=c>>5, KT=d>>4, lane=(c&31)+32*((d>>3)&1), e=d&7 -> Pt[((CT*16+KT)*64+lane)*8+e]
__global__ __launch_bounds__(256) void proto_kernel(
    const float* __restrict__ sums2, const float* __restrict__ counts2,
    const float* __restrict__ gpart, const float* __restrict__ proto_shrink,
    const float* __restrict__ logit_scale,
    unsigned short* __restrict__ Pt, float* __restrict__ outUC, int N_s)
{
    const int c = blockIdx.x, d = threadIdx.x;
    float ps = proto_shrink[0];
    float ab = 1.0f / (1.0f + __expf(-ps));
    ab = fminf(fmaxf(ab, 0.0f), 0.4f);
    const float sc = fminf(fmaxf(logit_scale[0], 1.0f), 100.0f);

    float sum  = sums2[(size_t)c * DD + d] + sums2[(size_t)(CC + c) * DD + d];
    float cntv = fmaxf(counts2[c] + counts2[CC + c], 1.0f);
    float g = 0.f;
    #pragma unroll
    for (int b = 0; b < 8; ++b) g += gpart[b * DD + d];
    g /= (float)N_s;

    float mean  = sum / cntv;
    float alpha = ab / sqrtf(cntv);
    float p = (1.0f - alpha) * mean + alpha * g;

    float ss = p * p;
    #pragma unroll
    for (int off = 32; off; off >>= 1) ss += __shfl_xor(ss, off);
    __shared__ float l4[4];
    if ((threadIdx.x & 63) == 0) l4[threadIdx.x >> 6] = ss;
    __syncthreads();
    ss = l4[0] + l4[1] + l4[2] + l4[3];
    float inv = sc / fmaxf(sqrtf(ss), 1e-8f);    // logit scale folded into prototype

    const int CT = c >> 5, KT = d >> 4;
    const int lane = (c & 31) + 32 * ((d >> 3) & 1);
    const int e = d & 7;
    Pt[(size_t)(((CT * 16 + KT) * 64 + lane)) * 8 + e] = f2bf(p * inv);
    if (d == 0) outUC[c] = (float)c;
}

// ---------------- K4: logits = normalize(q) @ (P*s)^T ----------------
// Persistent: grid 256 (1 block/CU), 1024 threads = 16 waves (4 waves/SIMD).
// Wave w owns 32 output cols: b[16] = 64 VGPR, capped at 128 by __launch_bounds__(1024,4).
// Q streams through double-buffered 64-row LDS chunks, single barrier per chunk;
// stage(c+1) co-scheduled with compute(c). BOTH single-touch streams nontemporal:
// NT stores (proven -27us vs plain, r12) + NT Q loads (L2 reserved for Pt/labels).
__global__ __launch_bounds__(1024, 4) void logits_kernel(
    const f32x4* __restrict__ Q, const unsigned short* __restrict__ Pt,
    float* __restrict__ out, int nch)
{
    __shared__ unsigned short A[2][64 * LDP2];   // 2 x 33.8 KB

    const int t  = threadIdx.x;
    const int w  = t >> 6, l = t & 63;
    const int lr = l & 31, lh = l >> 5;
    const int m0 = blockIdx.x * nch * 64;        // this block's row range
    const int sr = t >> 4, sc = t & 15;          // staging: 16 threads/row, 16 floats each

    // ---- B prologue: wave w's 32 columns (tile w), frag-ready coalesced loads ----
    // (cached loads: Pt is shared by all blocks, keep it in L2)
    short8 b[16];
    #pragma unroll
    for (int k = 0; k < 16; ++k)
        b[k] = *(const short8*)(Pt + (size_t)((w * 16 + k) * 64 + l) * 8);

    const f32x4* qbase = Q + (size_t)(m0 + sr) * 64 + sc * 4;

    f32x4 v[4];
    #pragma unroll
    for (int i = 0; i < 4; ++i) v[i] = ntload4(qbase + i);    // chunk 0 (64B contiguous)

    // stage chunk 0 -> A[0]
    {
        float ss = 0.f;
        #pragma unroll
        for (int i = 0; i < 4; ++i)
            ss += v[i][0]*v[i][0] + v[i][1]*v[i][1] + v[i][2]*v[i][2] + v[i][3]*v[i][3];
        ss += __shfl_xor(ss, 1); ss += __shfl_xor(ss, 2);
        ss += __shfl_xor(ss, 4); ss += __shfl_xor(ss, 8);
        float inv = 1.0f / fmaxf(sqrtf(ss), 1e-8f);
        unsigned short* dst = &A[0][sr * LDP2 + sc * 16];
        #pragma unroll
        for (int h = 0; h < 2; ++h) {
            short8 pk;
            f32x4 x = v[2*h], y = v[2*h+1];
            pk[0] = (short)f2bf(x[0]*inv); pk[1] = (short)f2bf(x[1]*inv);
            pk[2] = (short)f2bf(x[2]*inv); pk[3] = (short)f2bf(x[3]*inv);
            pk[4] = (short)f2bf(y[0]*inv); pk[5] = (short)f2bf(y[1]*inv);
            pk[6] = (short)f2bf(y[2]*inv); pk[7] = (short)f2bf(y[3]*inv);
            *(short8*)(dst + h * 8) = pk;
        }
    }
    if (nch > 1) {                                          // chunk 1 loads in flight
        const f32x4* src = qbase + (size_t)64 * 64;
        #pragma unroll
        for (int i = 0; i < 4; ++i) v[i] = ntload4(src + i);
    }
    __builtin_amdgcn_sched_barrier(0);
    asm volatile("s_waitcnt lgkmcnt(0)");
    __builtin_amdgcn_sched_barrier(0);
    __builtin_amdgcn_s_barrier();                // A[0] ready
    __builtin_amdgcn_sched_barrier(0);

    for (int c = 0; c < nch; ++c) {
        const int p = c & 1;

        // ---- stage chunk c+1 -> A[p^1] (same phase as compute; disjoint buffer) ----
        if (c + 1 < nch) {
            float ss = 0.f;
            #pragma unroll
            for (int i = 0; i < 4; ++i)
                ss += v[i][0]*v[i][0] + v[i][1]*v[i][1] + v[i][2]*v[i][2] + v[i][3]*v[i][3];
            ss += __shfl_xor(ss, 1); ss += __shfl_xor(ss, 2);
            ss += __shfl_xor(ss, 4); ss += __shfl_xor(ss, 8);
            float inv = 1.0f / fmaxf(sqrtf(ss), 1e-8f);
            unsigned short* dst = &A[p ^ 1][sr * LDP2 + sc * 16];
            #pragma unroll
            for (int h = 0; h < 2; ++h) {
                short8 pk;
                f32x4 x = v[2*h], y = v[2*h+1];
                pk[0] = (short)f2bf(x[0]*inv); pk[1] = (short)f2bf(x[1]*inv);
                pk[2] = (short)f2bf(x[2]*inv); pk[3] = (short)f2bf(x[3]*inv);
                pk[4] = (short)f2bf(y[0]*inv); pk[5] = (short)f2bf(y[1]*inv);
                pk[6] = (short)f2bf(y[2]*inv); pk[7] = (short)f2bf(y[3]*inv);
                *(short8*)(dst + h * 8) = pk;
            }
            if (c + 2 < nch) {                   // issue chunk c+2 loads
                const f32x4* src = qbase + (size_t)(c + 2) * 64 * 64;
                #pragma unroll
                for (int i = 0; i < 4; ++i) v[i] = ntload4(src + i);
            }
        }

        // ---- compute chunk c from A[p]: two 32-row subtiles, acc reused ----
        #pragma unroll
        for (int st = 0; st < 2; ++st) {
            f32x16 acc;
            #pragma unroll
            for (int r = 0; r < 16; ++r) acc[r] = 0.f;
            const unsigned short* ab = &A[p][(st * 32 + lr) * LDP2 + lh * 8];
            __builtin_amdgcn_s_setprio(1);
            #pragma unroll
            for (int k = 0; k < 16; ++k) {
                short8 af = *(const short8*)(ab + k * 16);
                acc = __builtin_amdgcn_mfma_f32_32x32x16_bf16(af, b[k], acc, 0, 0, 0);
            }
            __builtin_amdgcn_s_setprio(0);
            const int col = 32 * w + lr;
            const int rb  = m0 + c * 64 + st * 32 + 4 * lh;
            #pragma unroll
            for (int r = 0; r < 16; ++r) {
                int row = rb + (r & 3) + 8 * (r >> 2);
                __builtin_nontemporal_store(acc[r], &out[(size_t)row * CC + col]);
            }
        }

        __builtin_amdgcn_sched_barrier(0);
        asm volatile("s_waitcnt lgkmcnt(0)");    // my ds_writes (stage) + ds_reads (af) retired
        __builtin_amdgcn_sched_barrier(0);
        __builtin_amdgcn_s_barrier();            // A[p^1] ready for all / A[p] reads done
        __builtin_amdgcn_sched_barrier(0);
    }
}

extern "C" void kernel_launch(void* const* d_in, const int* in_sizes, int n_in,
                              void* d_out, int out_size, void* d_ws, size_t ws_size,
                              hipStream_t stream) {
    const float* S      = (const float*)d_in[0];
    const int*   labels = (const int*)d_in[1];
    const float* Qf     = (const float*)d_in[2];
    const float* lscale = (const float*)d_in[3];
    const float* pshr   = (const float*)d_in[4];

    const int N_s = in_sizes[0] / DD;     // 65536
    const int N_q = in_sizes[2] / DD;     // 131072

    float* sums2         = (float*)d_ws;                                   // 2*512*256*4
    float* counts2       = (float*)((char*)d_ws + 1048576);                // 2*512*4
    float* gpart         = (float*)((char*)d_ws + 1052672);                // 8*256*4
    unsigned short* Pt   = (unsigned short*)((char*)d_ws + 1060864);       // 512*256*2

    float* out   = (float*)d_out;
    float* outUC = out + (size_t)N_q * CC;

    const int nblk = 256;
    const int nch  = N_q / (nblk * 64);   // 8 chunks of 64 rows per block

    class_sum_kernel<<<2 * CC, 256, 0, stream>>>((const f32x4*)S, labels, sums2, counts2, N_s);
    centroid_kernel<<<8, 256, 0, stream>>>(sums2, gpart);
    proto_kernel<<<CC, 256, 0, stream>>>(sums2, counts2, gpart, pshr, lscale, Pt, outUC, N_s);
    logits_kernel<<<nblk, 1024, 0, stream>>>((const f32x4*)Qf, Pt, out, nch);
}

// Round 15
// 110.513 us; speedup vs baseline: 1.3012x; 1.3012x over previous
//
#include <hip/hip_runtime.h>

typedef __attribute__((ext_vector_type(4)))  float f32x4;
typedef __attribute__((ext_vector_type(16))) float f32x16;
typedef __attribute__((ext_vector_type(8)))  short short8;

#define DD 256          // feature dim
#define CC 512          // num classes
#define LDP2 264        // padded LDS row stride (bf16 elems): 528B

__device__ __forceinline__ unsigned short f2bf(float f) {
    union { float f; unsigned u; } x; x.f = f;
    unsigned r = x.u + 0x7FFFu + ((x.u >> 16) & 1u);   // RNE
    return (unsigned short)(r >> 16);
}

__device__ __forceinline__ f32x4 ntload4(const f32x4* p) {
    return __builtin_nontemporal_load(p);
}

// ---------------- K1: per-class segment sum of normalized support rows ----------------
__global__ __launch_bounds__(256) void class_sum_kernel(
    const f32x4* __restrict__ S, const int* __restrict__ labels,
    float* __restrict__ sums2, float* __restrict__ counts2, int N_s)
{
    const int c = blockIdx.x >> 1, half = blockIdx.x & 1;
    const int w = threadIdx.x >> 6, l = threadIdx.x & 63;
    const int seg  = N_s >> 3;
    const int base = half * (N_s >> 1) + w * seg;
    const int4* lab4 = (const int4*)(labels + base);
    const int iters = seg >> 8;

    float ax = 0.f, ay = 0.f, az = 0.f, aw = 0.f;
    int cnt = 0;

    int4 pf0 = lab4[l];
    int4 pf1 = (iters > 1) ? lab4[64 + l] : make_int4(-1, -1, -1, -1);

    for (int it = 0; it < iters; ++it) {
        int4 lv = pf0;
        pf0 = pf1;
        pf1 = (it + 2 < iters) ? lab4[(it + 2) * 64 + l] : make_int4(-1, -1, -1, -1);
        #pragma unroll
        for (int s = 0; s < 4; ++s) {
            int lab = (s == 0) ? lv.x : (s == 1) ? lv.y : (s == 2) ? lv.z : lv.w;
            unsigned long long m = __ballot(lab == c);
            cnt += __popcll(m);
            while (m) {
                int p0 = __ffsll((long long)m) - 1; m &= m - 1;
                int p1 = -1, p2 = -1, p3 = -1;
                if (m) { p1 = __ffsll((long long)m) - 1; m &= m - 1;
                    if (m) { p2 = __ffsll((long long)m) - 1; m &= m - 1;
                        if (m) { p3 = __ffsll((long long)m) - 1; m &= m - 1; } } }
                f32x4 v0 = ntload4(&S[(size_t)(base + (it * 64 + p0) * 4 + s) * 64 + l]);
                f32x4 v1 = {0,0,0,0}, v2 = {0,0,0,0}, v3 = {0,0,0,0};
                if (p1 >= 0) v1 = ntload4(&S[(size_t)(base + (it * 64 + p1) * 4 + s) * 64 + l]);
                if (p2 >= 0) v2 = ntload4(&S[(size_t)(base + (it * 64 + p2) * 4 + s) * 64 + l]);
                if (p3 >= 0) v3 = ntload4(&S[(size_t)(base + (it * 64 + p3) * 4 + s) * 64 + l]);
                float s0 = v0[0]*v0[0] + v0[1]*v0[1] + v0[2]*v0[2] + v0[3]*v0[3];
                float s1 = v1[0]*v1[0] + v1[1]*v1[1] + v1[2]*v1[2] + v1[3]*v1[3];
                float s2 = v2[0]*v2[0] + v2[1]*v2[1] + v2[2]*v2[2] + v2[3]*v2[3];
                float s3 = v3[0]*v3[0] + v3[1]*v3[1] + v3[2]*v3[2] + v3[3]*v3[3];
                #pragma unroll
                for (int off = 32; off; off >>= 1) {
                    s0 += __shfl_xor(s0, off);
                    s1 += __shfl_xor(s1, off);
                    s2 += __shfl_xor(s2, off);
                    s3 += __shfl_xor(s3, off);
                }
                float i0 = 1.0f / fmaxf(sqrtf(s0), 1e-8f);
                ax += v0[0]*i0; ay += v0[1]*i0; az += v0[2]*i0; aw += v0[3]*i0;
                if (p1 >= 0) { float i1 = 1.0f / fmaxf(sqrtf(s1), 1e-8f);
                    ax += v1[0]*i1; ay += v1[1]*i1; az += v1[2]*i1; aw += v1[3]*i1; }
                if (p2 >= 0) { float i2 = 1.0f / fmaxf(sqrtf(s2), 1e-8f);
                    ax += v2[0]*i2; ay += v2[1]*i2; az += v2[2]*i2; aw += v2[3]*i2; }
                if (p3 >= 0) { float i3 = 1.0f / fmaxf(sqrtf(s3), 1e-8f);
                    ax += v3[0]*i3; ay += v3[1]*i3; az += v3[2]*i3; aw += v3[3]*i3; }
            }
        }
    }

    __shared__ float lred[4][DD];
    __shared__ float lcnt[4];
    lred[w][4*l+0] = ax; lred[w][4*l+1] = ay; lred[w][4*l+2] = az; lred[w][4*l+3] = aw;
    if (l == 0) lcnt[w] = (float)cnt;
    __syncthreads();
    int t = threadIdx.x;
    sums2[(size_t)(half * CC + c) * DD + t] = lred[0][t] + lred[1][t] + lred[2][t] + lred[3][t];
    if (t == 0) counts2[half * CC + c] = lcnt[0] + lcnt[1] + lcnt[2] + lcnt[3];
}

// ---------------- K2: centroid partials (8 blocks, no atomics) ----------------
__global__ __launch_bounds__(256) void centroid_kernel(
    const float* __restrict__ sums2, float* __restrict__ gpart)
{
    const int d = threadIdx.x, b = blockIdx.x;
    float s = 0.f;
    for (int j = 0; j < 64; ++j) {
        int c = b * 64 + j;
        s += sums2[(size_t)c * DD + d] + sums2[(size_t)(CC + c) * DD + d];
    }
    gpart[b * DD + d] = s;
}

// ---------------- K3: prototypes -> bf16 Pt in MFMA B-frag layout, SCALE FOLDED IN ----
// Pt element for (class c, dim d):
//   CT=c>>5, KT=d>>4, lane=(c&31)+32*((d>>3)&1), e=d&7 -> Pt[((CT*16+KT)*64+lane)*8+e]
__global__ __launch_bounds__(256) void proto_kernel(
    const float* __restrict__ sums2, const float* __restrict__ counts2,
    const float* __restrict__ gpart, const float* __restrict__ proto_shrink,
    const float* __restrict__ logit_scale,
    unsigned short* __restrict__ Pt, float* __restrict__ outUC, int N_s)
{
    const int c = blockIdx.x, d = threadIdx.x;
    float ps = proto_shrink[0];
    float ab = 1.0f / (1.0f + __expf(-ps));
    ab = fminf(fmaxf(ab, 0.0f), 0.4f);
    const float sc = fminf(fmaxf(logit_scale[0], 1.0f), 100.0f);

    float sum  = sums2[(size_t)c * DD + d] + sums2[(size_t)(CC + c) * DD + d];
    float cntv = fmaxf(counts2[c] + counts2[CC + c], 1.0f);
    float g = 0.f;
    #pragma unroll
    for (int b = 0; b < 8; ++b) g += gpart[b * DD + d];
    g /= (float)N_s;

    float mean  = sum / cntv;
    float alpha = ab / sqrtf(cntv);
    float p = (1.0f - alpha) * mean + alpha * g;

    float ss = p * p;
    #pragma unroll
    for (int off = 32; off; off >>= 1) ss += __shfl_xor(ss, off);
    __shared__ float l4[4];
    if ((threadIdx.x & 63) == 0) l4[threadIdx.x >> 6] = ss;
    __syncthreads();
    ss = l4[0] + l4[1] + l4[2] + l4[3];
    float inv = sc / fmaxf(sqrtf(ss), 1e-8f);    // logit scale folded into prototype

    const int CT = c >> 5, KT = d >> 4;
    const int lane = (c & 31) + 32 * ((d >> 3) & 1);
    const int e = d & 7;
    Pt[(size_t)(((CT * 16 + KT) * 64 + lane)) * 8 + e] = f2bf(p * inv);
    if (d == 0) outUC[c] = (float)c;
}

// ---------------- K4: logits = normalize(q) @ (P*s)^T ----------------
// Persistent: grid 256 (1 block/CU), 1024 threads = 16 waves (4 waves/SIMD).
// Wave w owns 32 output cols: b[16] = 64 VGPR, capped at 128 by __launch_bounds__(1024,4).
// Q streams through double-buffered 64-row LDS chunks, single barrier per chunk;
// stage(c+1) co-scheduled with compute(c). Measured-best cache policy (r7/r12/r14 A/B):
// NT stores (no write-allocate: -27us) + CACHED Q loads (NT loads cost +33us).
__global__ __launch_bounds__(1024, 4) void logits_kernel(
    const float4* __restrict__ Q, const unsigned short* __restrict__ Pt,
    float* __restrict__ out, int nch)
{
    __shared__ unsigned short A[2][64 * LDP2];   // 2 x 33.8 KB

    const int t  = threadIdx.x;
    const int w  = t >> 6, l = t & 63;
    const int lr = l & 31, lh = l >> 5;
    const int m0 = blockIdx.x * nch * 64;        // this block's row range
    const int sr = t >> 4, sc = t & 15;          // staging: 16 threads/row, 16 floats each

    // ---- B prologue: wave w's 32 columns (tile w), frag-ready coalesced loads ----
    short8 b[16];
    #pragma unroll
    for (int k = 0; k < 16; ++k)
        b[k] = *(const short8*)(Pt + (size_t)((w * 16 + k) * 64 + l) * 8);

    const float4* qbase = Q + (size_t)(m0 + sr) * 64 + sc * 4;

    float4 v[4];
    #pragma unroll
    for (int i = 0; i < 4; ++i) v[i] = qbase[i];            // chunk 0 (64B contiguous)

    // stage chunk 0 -> A[0]
    {
        float ss = 0.f;
        #pragma unroll
        for (int i = 0; i < 4; ++i)
            ss += v[i].x*v[i].x + v[i].y*v[i].y + v[i].z*v[i].z + v[i].w*v[i].w;
        ss += __shfl_xor(ss, 1); ss += __shfl_xor(ss, 2);
        ss += __shfl_xor(ss, 4); ss += __shfl_xor(ss, 8);
        float inv = 1.0f / fmaxf(sqrtf(ss), 1e-8f);
        unsigned short* dst = &A[0][sr * LDP2 + sc * 16];
        #pragma unroll
        for (int h = 0; h < 2; ++h) {
            short8 pk;
            float4 x = v[2*h], y = v[2*h+1];
            pk[0] = (short)f2bf(x.x*inv); pk[1] = (short)f2bf(x.y*inv);
            pk[2] = (short)f2bf(x.z*inv); pk[3] = (short)f2bf(x.w*inv);
            pk[4] = (short)f2bf(y.x*inv); pk[5] = (short)f2bf(y.y*inv);
            pk[6] = (short)f2bf(y.z*inv); pk[7] = (short)f2bf(y.w*inv);
            *(short8*)(dst + h * 8) = pk;
        }
    }
    if (nch > 1) {                                          // chunk 1 loads in flight
        const float4* src = qbase + (size_t)64 * 64;
        #pragma unroll
        for (int i = 0; i < 4; ++i) v[i] = src[i];
    }
    __builtin_amdgcn_sched_barrier(0);
    asm volatile("s_waitcnt lgkmcnt(0)");
    __builtin_amdgcn_sched_barrier(0);
    __builtin_amdgcn_s_barrier();                // A[0] ready
    __builtin_amdgcn_sched_barrier(0);

    for (int c = 0; c < nch; ++c) {
        const int p = c & 1;

        // ---- stage chunk c+1 -> A[p^1] (same phase as compute; disjoint buffer) ----
        if (c + 1 < nch) {
            float ss = 0.f;
            #pragma unroll
            for (int i = 0; i < 4; ++i)
                ss += v[i].x*v[i].x + v[i].y*v[i].y + v[i].z*v[i].z + v[i].w*v[i].w;
            ss += __shfl_xor(ss, 1); ss += __shfl_xor(ss, 2);
            ss += __shfl_xor(ss, 4); ss += __shfl_xor(ss, 8);
            float inv = 1.0f / fmaxf(sqrtf(ss), 1e-8f);
            unsigned short* dst = &A[p ^ 1][sr * LDP2 + sc * 16];
            #pragma unroll
            for (int h = 0; h < 2; ++h) {
                short8 pk;
                float4 x = v[2*h], y = v[2*h+1];
                pk[0] = (short)f2bf(x.x*inv); pk[1] = (short)f2bf(x.y*inv);
                pk[2] = (short)f2bf(x.z*inv); pk[3] = (short)f2bf(x.w*inv);
                pk[4] = (short)f2bf(y.x*inv); pk[5] = (short)f2bf(y.y*inv);
                pk[6] = (short)f2bf(y.z*inv); pk[7] = (short)f2bf(y.w*inv);
                *(short8*)(dst + h * 8) = pk;
            }
            if (c + 2 < nch) {                   // issue chunk c+2 loads
                const float4* src = qbase + (size_t)(c + 2) * 64 * 64;
                #pragma unroll
                for (int i = 0; i < 4; ++i) v[i] = src[i];
            }
        }

        // ---- compute chunk c from A[p]: two 32-row subtiles, acc reused ----
        #pragma unroll
        for (int st = 0; st < 2; ++st) {
            f32x16 acc;
            #pragma unroll
            for (int r = 0; r < 16; ++r) acc[r] = 0.f;
            const unsigned short* ab = &A[p][(st * 32 + lr) * LDP2 + lh * 8];
            __builtin_amdgcn_s_setprio(1);
            #pragma unroll
            for (int k = 0; k < 16; ++k) {
                short8 af = *(const short8*)(ab + k * 16);
                acc = __builtin_amdgcn_mfma_f32_32x32x16_bf16(af, b[k], acc, 0, 0, 0);
            }
            __builtin_amdgcn_s_setprio(0);
            const int col = 32 * w + lr;
            const int rb  = m0 + c * 64 + st * 32 + 4 * lh;
            #pragma unroll
            for (int r = 0; r < 16; ++r) {
                int row = rb + (r & 3) + 8 * (r >> 2);
                __builtin_nontemporal_store(acc[r], &out[(size_t)row * CC + col]);
            }
        }

        __builtin_amdgcn_sched_barrier(0);
        asm volatile("s_waitcnt lgkmcnt(0)");    // my ds_writes (stage) + ds_reads (af) retired
        __builtin_amdgcn_sched_barrier(0);
        __builtin_amdgcn_s_barrier();            // A[p^1] ready for all / A[p] reads done
        __builtin_amdgcn_sched_barrier(0);
    }
}

extern "C" void kernel_launch(void* const* d_in, const int* in_sizes, int n_in,
                              void* d_out, int out_size, void* d_ws, size_t ws_size,
                              hipStream_t stream) {
    const float* S      = (const float*)d_in[0];
    const int*   labels = (const int*)d_in[1];
    const float* Qf     = (const float*)d_in[2];
    const float* lscale = (const float*)d_in[3];
    const float* pshr   = (const float*)d_in[4];

    const int N_s = in_sizes[0] / DD;     // 65536
    const int N_q = in_sizes[2] / DD;     // 131072

    float* sums2         = (float*)d_ws;                                   // 2*512*256*4
    float* counts2       = (float*)((char*)d_ws + 1048576);                // 2*512*4
    float* gpart         = (float*)((char*)d_ws + 1052672);                // 8*256*4
    unsigned short* Pt   = (unsigned short*)((char*)d_ws + 1060864);       // 512*256*2

    float* out   = (float*)d_out;
    float* outUC = out + (size_t)N_q * CC;

    const int nblk = 256;
    const int nch  = N_q / (nblk * 64);   // 8 chunks of 64 rows per block

    class_sum_kernel<<<2 * CC, 256, 0, stream>>>((const f32x4*)S, labels, sums2, counts2, N_s);
    centroid_kernel<<<8, 256, 0, stream>>>(sums2, gpart);
    proto_kernel<<<CC, 256, 0, stream>>>(sums2, counts2, gpart, pshr, lscale, Pt, outUC, N_s);
    logits_kernel<<<nblk, 1024, 0, stream>>>((const float4*)Qf, Pt, out, nch);
}